// Round 1
// baseline (303.735 us; speedup 1.0000x reference)
//
#include <hip/hip_runtime.h>
#include <math.h>

#define QDIM 64
#define HDIM 64
#define M_NB 64
#define ATOMS_PER_BLOCK 4
#define BLOCK 256

// Fused kernel: per-atom MLP chain rule + minimum-image r2 + r2-weighted
// gradient contraction, reduced to 3 partial sums per block.
// One wave (64 lanes) per atom; 4 atoms per 256-thread block.
__global__ __launch_bounds__(BLOCK) void tnep_main(
    const float* __restrict__ desc,   // [N,Q]
    const float* __restrict__ grad,   // [N,M,3,Q]
    const float* __restrict__ pos,    // [N,3]
    const float* __restrict__ box,    // [3,3]
    const float* __restrict__ W0,     // [T,Q,H]
    const float* __restrict__ b0,     // [T,H]
    const float* __restrict__ W1,     // [T,H]
    const int*   __restrict__ Z,      // [N]
    const int*   __restrict__ gidx,   // [N,M]
    float* __restrict__ part,         // [3, gridDim.x]
    int nblk)
{
    __shared__ __align__(16) float desc_s[ATOMS_PER_BLOCK][QDIM];
    __shared__ __align__(16) float g_s[ATOMS_PER_BLOCK][HDIM];
    __shared__ __align__(16) float de_s[ATOMS_PER_BLOCK][QDIM];
    __shared__ __align__(16) float r2_s[ATOMS_PER_BLOCK][M_NB];
    __shared__ float red_s[3][ATOMS_PER_BLOCK];

    const int tid  = threadIdx.x;
    const int w    = tid >> 6;      // wave index within block = atom slot
    const int lane = tid & 63;
    const int n    = blockIdx.x * ATOMS_PER_BLOCK + w;

    // ---- stage descriptors (coalesced) ----
    desc_s[w][lane] = desc[n * QDIM + lane];

    // ---- r2 for neighbor m = lane (minimum image; j==n gives exactly 0) ----
    {
        int j = gidx[n * M_NB + lane];
        float B[9];
        #pragma unroll
        for (int k = 0; k < 9; ++k) B[k] = box[k];
        float det = B[0]*(B[4]*B[8]-B[5]*B[7])
                  - B[1]*(B[3]*B[8]-B[5]*B[6])
                  + B[2]*(B[3]*B[7]-B[4]*B[6]);
        float inv = 1.0f / det;
        float IB[9];
        IB[0] = (B[4]*B[8]-B[5]*B[7])*inv;
        IB[1] = (B[2]*B[7]-B[1]*B[8])*inv;
        IB[2] = (B[1]*B[5]-B[2]*B[4])*inv;
        IB[3] = (B[5]*B[6]-B[3]*B[8])*inv;
        IB[4] = (B[0]*B[8]-B[2]*B[6])*inv;
        IB[5] = (B[2]*B[3]-B[0]*B[5])*inv;
        IB[6] = (B[3]*B[7]-B[4]*B[6])*inv;
        IB[7] = (B[1]*B[6]-B[0]*B[7])*inv;
        IB[8] = (B[0]*B[4]-B[1]*B[3])*inv;
        float dx = pos[j*3+0] - pos[n*3+0];
        float dy = pos[j*3+1] - pos[n*3+1];
        float dz = pos[j*3+2] - pos[n*3+2];
        // s = d @ inv_box
        float sx = dx*IB[0] + dy*IB[3] + dz*IB[6];
        float sy = dx*IB[1] + dy*IB[4] + dz*IB[7];
        float sz = dx*IB[2] + dy*IB[5] + dz*IB[8];
        sx -= rintf(sx); sy -= rintf(sy); sz -= rintf(sz);  // rint = half-to-even, matches jnp.round
        // d' = s @ box
        float ex = sx*B[0] + sy*B[3] + sz*B[6];
        float ey = sx*B[1] + sy*B[4] + sz*B[7];
        float ez = sx*B[2] + sy*B[5] + sz*B[8];
        r2_s[w][lane] = ex*ex + ey*ey + ez*ez;
    }
    __syncthreads();

    // ---- MLP forward: t[h] = b0 + desc . W0[:,h]  (lane = h) ----
    const int z = Z[n];
    const float* W0t = W0 + (size_t)z * QDIM * HDIM;
    float t = b0[z * HDIM + lane];
    #pragma unroll 8
    for (int q = 0; q < QDIM; ++q)
        t += desc_s[w][q] * W0t[q * HDIM + lane];   // coalesced, L1-resident (T=4)
    float ha = tanhf(t);
    g_s[w][lane] = (1.0f - ha * ha) * W1[z * HDIM + lane];
    __syncthreads();

    // ---- chain rule: de_dq[q] = g . W0[q,:]  (lane = q, float4 over h) ----
    {
        float de = 0.0f;
        const float* W0row = W0t + lane * HDIM;     // 16B-aligned (lane*256B)
        #pragma unroll
        for (int h4 = 0; h4 < HDIM / 4; ++h4) {
            float4 wv = *(const float4*)(W0row + h4 * 4);
            float4 gv = *(const float4*)(&g_s[w][h4 * 4]);
            de += wv.x*gv.x + wv.y*gv.y + wv.z*gv.z + wv.w*gv.w;
        }
        de_s[w][lane] = de;
    }
    __syncthreads();

    // ---- Phase B: stream this atom's 48KB gradient block, float4/lane ----
    // flat float index f0 within the atom block: m = f0/192, c = (f0%192)>>6, q0 = f0&63
    float acc0 = 0.f, acc1 = 0.f, acc2 = 0.f;
    const float* base = grad + (size_t)n * M_NB * 3 * QDIM;
    #pragma unroll 4
    for (int i = 0; i < (M_NB * 3 * QDIM) / (64 * 4); ++i) {   // 48 iters
        int f0 = (i * 64 + lane) * 4;
        float4 gv = *(const float4*)(base + f0);
        int m   = f0 / 192;
        int rem = f0 - m * 192;
        int c   = rem >> 6;
        int q0  = rem & 63;
        float4 dq = *(const float4*)(&de_s[w][q0]);            // ds_read_b128, 2-way = free
        float partial = gv.x*dq.x + gv.y*dq.y + gv.z*dq.z + gv.w*dq.w;
        float contrib = r2_s[w][m] * partial;
        acc0 += (c == 0) ? contrib : 0.f;                      // predicated, no divergence
        acc1 += (c == 1) ? contrib : 0.f;
        acc2 += (c == 2) ? contrib : 0.f;
    }

    // ---- wave reduce (64 lanes) ----
    #pragma unroll
    for (int off = 32; off > 0; off >>= 1) {
        acc0 += __shfl_down(acc0, off, 64);
        acc1 += __shfl_down(acc1, off, 64);
        acc2 += __shfl_down(acc2, off, 64);
    }
    if (lane == 0) { red_s[0][w] = acc0; red_s[1][w] = acc1; red_s[2][w] = acc2; }
    __syncthreads();
    if (tid < 3) {
        float s = red_s[tid][0] + red_s[tid][1] + red_s[tid][2] + red_s[tid][3];
        part[tid * nblk + blockIdx.x] = s;
    }
}

__global__ __launch_bounds__(256) void tnep_reduce(
    const float* __restrict__ part, float* __restrict__ out, int nblk)
{
    __shared__ float red[256];
    int t = threadIdx.x;
    for (int c = 0; c < 3; ++c) {
        float s = 0.f;
        for (int b = t; b < nblk; b += 256) s += part[c * nblk + b];
        red[t] = s;
        __syncthreads();
        for (int off = 128; off > 0; off >>= 1) {
            if (t < off) red[t] += red[t + off];
            __syncthreads();
        }
        if (t == 0) out[c] = -red[0];   // dipole = -sum
        __syncthreads();
    }
}

extern "C" void kernel_launch(void* const* d_in, const int* in_sizes, int n_in,
                              void* d_out, int out_size, void* d_ws, size_t ws_size,
                              hipStream_t stream) {
    const float* desc = (const float*)d_in[0];   // [N,Q]
    const float* grad = (const float*)d_in[1];   // [N,M,3,Q]
    const float* pos  = (const float*)d_in[2];   // [N,3]
    const float* box  = (const float*)d_in[3];   // [3,3]
    const float* W0   = (const float*)d_in[4];   // [T,Q,H]
    const float* b0   = (const float*)d_in[5];   // [T,H]
    const float* W1   = (const float*)d_in[6];   // [T,H]
    const int*   Z    = (const int*)d_in[7];     // [N]
    const int*   gidx = (const int*)d_in[8];     // [N,M]

    const int N    = in_sizes[0] / QDIM;         // 4096
    const int nblk = N / ATOMS_PER_BLOCK;        // 1024

    float* part = (float*)d_ws;                  // [3, nblk] = 12 KB

    tnep_main<<<nblk, BLOCK, 0, stream>>>(desc, grad, pos, box, W0, b0, W1,
                                          Z, gidx, part, nblk);
    tnep_reduce<<<1, 256, 0, stream>>>(part, (float*)d_out, nblk);
}

// Round 3
// 291.061 us; speedup vs baseline: 1.0435x; 1.0435x over previous
//
#include <hip/hip_runtime.h>
#include <math.h>

#define QDIM 64
#define HDIM 64
#define M_NB 64
#define BLOCK 256

typedef float f4 __attribute__((ext_vector_type(4)));   // native vec for nontemporal builtin

// ---------------- K1: per-atom MLP chain rule + minimum-image r2 ----------------
// One wave per atom, 4 atoms per block. Writes de_dq[N,64] and r2[N,64] to ws.
__global__ __launch_bounds__(BLOCK) void tnep_setup(
    const float* __restrict__ desc,   // [N,Q]
    const float* __restrict__ pos,    // [N,3]
    const float* __restrict__ box,    // [3,3]
    const float* __restrict__ W0,     // [T,Q,H]
    const float* __restrict__ b0,     // [T,H]
    const float* __restrict__ W1,     // [T,H]
    const int*   __restrict__ Z,      // [N]
    const int*   __restrict__ gidx,   // [N,M]
    float* __restrict__ de_out,       // [N,64]
    float* __restrict__ r2_out)       // [N,64]
{
    __shared__ __align__(16) float desc_s[4][QDIM];
    __shared__ __align__(16) float g_s[4][HDIM];

    const int tid  = threadIdx.x;
    const int w    = tid >> 6;
    const int lane = tid & 63;
    const int n    = blockIdx.x * 4 + w;

    desc_s[w][lane] = desc[n * QDIM + lane];

    // ---- r2 for neighbor m = lane (minimum image; j==n gives exactly 0) ----
    {
        int j = gidx[n * M_NB + lane];
        float B[9];
        #pragma unroll
        for (int k = 0; k < 9; ++k) B[k] = box[k];
        float det = B[0]*(B[4]*B[8]-B[5]*B[7])
                  - B[1]*(B[3]*B[8]-B[5]*B[6])
                  + B[2]*(B[3]*B[7]-B[4]*B[6]);
        float inv = 1.0f / det;
        float IB[9];
        IB[0] = (B[4]*B[8]-B[5]*B[7])*inv;
        IB[1] = (B[2]*B[7]-B[1]*B[8])*inv;
        IB[2] = (B[1]*B[5]-B[2]*B[4])*inv;
        IB[3] = (B[5]*B[6]-B[3]*B[8])*inv;
        IB[4] = (B[0]*B[8]-B[2]*B[6])*inv;
        IB[5] = (B[2]*B[3]-B[0]*B[5])*inv;
        IB[6] = (B[3]*B[7]-B[4]*B[6])*inv;
        IB[7] = (B[1]*B[6]-B[0]*B[7])*inv;
        IB[8] = (B[0]*B[4]-B[1]*B[3])*inv;
        float dx = pos[j*3+0] - pos[n*3+0];
        float dy = pos[j*3+1] - pos[n*3+1];
        float dz = pos[j*3+2] - pos[n*3+2];
        float sx = dx*IB[0] + dy*IB[3] + dz*IB[6];
        float sy = dx*IB[1] + dy*IB[4] + dz*IB[7];
        float sz = dx*IB[2] + dy*IB[5] + dz*IB[8];
        sx -= rintf(sx); sy -= rintf(sy); sz -= rintf(sz);
        float ex = sx*B[0] + sy*B[3] + sz*B[6];
        float ey = sx*B[1] + sy*B[4] + sz*B[7];
        float ez = sx*B[2] + sy*B[5] + sz*B[8];
        r2_out[n * M_NB + lane] = ex*ex + ey*ey + ez*ez;
    }
    __syncthreads();

    // ---- MLP forward: lane = h ----
    const int z = Z[n];
    const float* W0t = W0 + (size_t)z * QDIM * HDIM;
    float t = b0[z * HDIM + lane];
    #pragma unroll 8
    for (int q = 0; q < QDIM; ++q)
        t += desc_s[w][q] * W0t[q * HDIM + lane];
    float ha = tanhf(t);
    g_s[w][lane] = (1.0f - ha * ha) * W1[z * HDIM + lane];
    __syncthreads();

    // ---- chain rule: de_dq[q] = g . W0[q,:]  (lane = q) ----
    {
        float de = 0.0f;
        const float* W0row = W0t + lane * HDIM;
        #pragma unroll
        for (int h4 = 0; h4 < HDIM / 4; ++h4) {
            float4 wv = *(const float4*)(W0row + h4 * 4);
            float4 gv = *(const float4*)(&g_s[w][h4 * 4]);
            de += wv.x*gv.x + wv.y*gv.y + wv.z*gv.z + wv.w*gv.w;
        }
        de_out[n * QDIM + lane] = de;
    }
}

// ---------------- K2: pure streamer ----------------
// Block b owns atoms 4b..4b+3 (192 KB contiguous). Thread t reads float4
// #(i*256+t) of the block region: at each step the block touches one
// contiguous 4 KB line. q0 = 4*(t&15) is FIXED per thread -> de fragment in
// registers; m/c advance incrementally; c-dispatch = 3 FMAs with {0,1}
// selector registers.
__global__ __launch_bounds__(BLOCK) void tnep_stream(
    const float* __restrict__ grad,   // [N,M,3,Q]
    const float* __restrict__ de,     // [N,64]
    const float* __restrict__ r2w,    // [N,64]
    float* __restrict__ part,         // [3, nblk]
    int nblk)
{
    __shared__ __align__(16) float r2_s[256];   // 4 atoms x 64
    __shared__ __align__(16) float de_s[256];   // 4 atoms x 64
    __shared__ float red_s[3][4];

    const int t    = threadIdx.x;
    const int blk  = blockIdx.x;
    const int w    = t >> 6;
    const int lane = t & 63;

    r2_s[t] = r2w[blk * 256 + t];
    de_s[t] = de[blk * 256 + t];
    __syncthreads();

    const int g16 = t >> 4;            // 0..15: which c-row group within 4KB step
    const int q0  = 4 * (t & 15);      // fixed q-fragment
    const int gm  = g16 % 3;
    const int m0  = g16 / 3;           // m at start of each atom

    // selector s{k}[rr] = ((gm+rr)%3 == k), as floats for fmac accumulation
    float s0[3], s1[3], s2[3];
    int   dm[3];
    #pragma unroll
    for (int rr = 0; rr < 3; ++rr) {
        int c = gm + rr; if (c >= 3) c -= 3;
        s0[rr] = (c == 0) ? 1.f : 0.f;
        s1[rr] = (c == 1) ? 1.f : 0.f;
        s2[rr] = (c == 2) ? 1.f : 0.f;
        dm[rr] = 5 + ((c == 2) ? 1 : 0);   // m advance for next iter
    }

    const f4* gp = (const f4*)grad + (size_t)blk * 12288 + t;

    float acc0 = 0.f, acc1 = 0.f, acc2 = 0.f;
    #pragma unroll
    for (int a = 0; a < 4; ++a) {
        f4 df = *(const f4*)(&de_s[a * 64 + q0]);
        int m = m0;
        #pragma unroll
        for (int ii = 0; ii < 12; ++ii) {
            const int i = a * 12 + ii;
            f4 gv = __builtin_nontemporal_load(gp + i * 256);
            float r2v = r2_s[a * 64 + m];
            float dot = gv.x*df.x + gv.y*df.y + gv.z*df.z + gv.w*df.w;
            float contrib = r2v * dot;
            const int rr = ii % 3;
            acc0 = fmaf(s0[rr], contrib, acc0);
            acc1 = fmaf(s1[rr], contrib, acc1);
            acc2 = fmaf(s2[rr], contrib, acc2);
            m += dm[rr];
        }
    }

    #pragma unroll
    for (int off = 32; off > 0; off >>= 1) {
        acc0 += __shfl_down(acc0, off, 64);
        acc1 += __shfl_down(acc1, off, 64);
        acc2 += __shfl_down(acc2, off, 64);
    }
    if (lane == 0) { red_s[0][w] = acc0; red_s[1][w] = acc1; red_s[2][w] = acc2; }
    __syncthreads();
    if (t < 3) {
        part[t * nblk + blk] = red_s[t][0] + red_s[t][1] + red_s[t][2] + red_s[t][3];
    }
}

// ---------------- K3: final reduce ----------------
__global__ __launch_bounds__(256) void tnep_reduce(
    const float* __restrict__ part, float* __restrict__ out, int nblk)
{
    const int t = threadIdx.x, w = t >> 6, lane = t & 63;
    if (w < 3) {
        float s = 0.f;
        for (int b = lane; b < nblk; b += 64) s += part[w * nblk + b];
        #pragma unroll
        for (int off = 32; off > 0; off >>= 1) s += __shfl_down(s, off, 64);
        if (lane == 0) out[w] = -s;
    }
}

extern "C" void kernel_launch(void* const* d_in, const int* in_sizes, int n_in,
                              void* d_out, int out_size, void* d_ws, size_t ws_size,
                              hipStream_t stream) {
    const float* desc = (const float*)d_in[0];
    const float* grad = (const float*)d_in[1];
    const float* pos  = (const float*)d_in[2];
    const float* box  = (const float*)d_in[3];
    const float* W0   = (const float*)d_in[4];
    const float* b0   = (const float*)d_in[5];
    const float* W1   = (const float*)d_in[6];
    const int*   Z    = (const int*)d_in[7];
    const int*   gidx = (const int*)d_in[8];

    const int N    = in_sizes[0] / QDIM;   // 4096
    const int nblk = N / 4;                // 1024 (blocks for both K1 and K2)

    float* part  = (float*)d_ws;                    // [3, nblk]
    float* de_ws = (float*)d_ws + 8192;             // [N, 64]
    float* r2_ws = de_ws + (size_t)N * 64;          // [N, 64]

    tnep_setup<<<nblk, BLOCK, 0, stream>>>(desc, pos, box, W0, b0, W1, Z, gidx,
                                           de_ws, r2_ws);
    tnep_stream<<<nblk, BLOCK, 0, stream>>>(grad, de_ws, r2_ws, part, nblk);
    tnep_reduce<<<1, BLOCK, 0, stream>>>(part, (float*)d_out, nblk);
}